// Round 4
// baseline (2029.394 us; speedup 1.0000x reference)
//
#include <hip/hip_runtime.h>

#define N_NODES 20000
#define D 128
#define E_EDGES 320000
#define G 100
#define L_LAYERS 6
#define IN_DIM 5
#define ZROW (IN_DIM + D)
#define CUTOFF_V 10.0f
#define LOG2F_ 0.69314718055994530942f

typedef __attribute__((ext_vector_type(8))) short bf16x8;
typedef __attribute__((ext_vector_type(4))) float f32x4;
typedef unsigned short ushort_t;
typedef unsigned int uint_t;

__device__ __forceinline__ float sspf(float x) {
    return fmaxf(x, 0.0f) + __logf(1.0f + __expf(-fabsf(x))) - LOG2F_;
}

__device__ __forceinline__ ushort_t f2bf(float f) {
    union { float f; uint_t u; } x; x.f = f;
    uint_t r = ((x.u >> 16) & 1u) + 0x7fffu;
    return (ushort_t)((x.u + r) >> 16);
}

__device__ __forceinline__ uint_t pack2(float a, float b) {
    return (uint_t)f2bf(a) | ((uint_t)f2bf(b) << 16);
}

__device__ __forceinline__ f32x4 mfma_bf16(bf16x8 a, bf16x8 b, f32x4 c) {
    return __builtin_amdgcn_mfma_f32_16x16x32_bf16(a, b, c, 0, 0, 0);
}

// ---------------------------------------------------------------------------
__global__ void embed_kernel(const float* __restrict__ z,
                             const float* __restrict__ ew,
                             const float* __restrict__ eb,
                             float* __restrict__ h) {
    int n = blockIdx.x;
    int d = threadIdx.x;
    const float* zr = z + (size_t)n * ZROW;
    float acc = eb[d] + zr[IN_DIM + d];
#pragma unroll
    for (int k = 0; k < IN_DIM; ++k) acc += zr[k] * ew[d * IN_DIM + k];
    h[(size_t)n * D + d] = acc;
}

// ---------------------------------------------------------------------------
// mlp_w1 [L][D][G] -> bf16 [L][D][128] zero-padded in k
__global__ void convw1_kernel(const float* __restrict__ w1, ushort_t* __restrict__ out) {
    int idx = blockIdx.x * 256 + threadIdx.x;
    int k = idx & 127;
    int nl = idx >> 7;
    out[idx] = (k < G) ? f2bf(w1[(size_t)nl * G + k]) : (ushort_t)0;
}

__global__ void castbf_kernel(const float* __restrict__ src, ushort_t* __restrict__ dst) {
    int i = blockIdx.x * 256 + threadIdx.x;
    dst[i] = f2bf(src[i]);
}

// ---------------------------------------------------------------------------
// CSR build (edge graph constant across layers)
__global__ void hist_kernel(const int* __restrict__ ei, int* __restrict__ deg) {
    int e = blockIdx.x * 256 + threadIdx.x;
    atomicAdd(&deg[ei[E_EDGES + e]], 1);
}

__global__ __launch_bounds__(1024) void scan_kernel(const int* __restrict__ deg,
                                                    int* __restrict__ row_start,
                                                    int* __restrict__ cursor) {
    __shared__ int wsum[16];
    int t = threadIdx.x;
    const int CH = (N_NODES + 1023) / 1024;
    int base = t * CH;
    int s = 0;
    for (int i = 0; i < CH; ++i) {
        int idx = base + i;
        if (idx < N_NODES) s += deg[idx];
    }
    int lane = t & 63, wid = t >> 6;
    int v = s;
    for (int o = 1; o < 64; o <<= 1) {
        int u = __shfl_up(v, o, 64);
        if (lane >= o) v += u;
    }
    if (lane == 63) wsum[wid] = v;
    __syncthreads();
    if (t == 0) {
        int acc = 0;
        for (int i = 0; i < 16; ++i) { int tmp = wsum[i]; wsum[i] = acc; acc += tmp; }
    }
    __syncthreads();
    int run = v - s + wsum[wid];
    for (int i = 0; i < CH; ++i) {
        int idx = base + i;
        if (idx < N_NODES) {
            row_start[idx] = run;
            cursor[idx] = run;
            run += deg[idx];
        }
    }
    if (t == 0) row_start[N_NODES] = E_EDGES;
}

__global__ void scatter_perm_kernel(const int* __restrict__ ei, int* __restrict__ cursor,
                                    int* __restrict__ perm, int* __restrict__ src_p) {
    int e = blockIdx.x * 256 + threadIdx.x;
    int d = ei[E_EDGES + e];
    int p = atomicAdd(&cursor[d], 1);
    perm[p] = e;
    src_p[p] = ei[e];
}

// ---------------------------------------------------------------------------
// One-time: attr_bf[i][0:128] = bf16(edge_attr[perm[i]][0:100]) zero-padded.
// 8 rows/block: each half-wave (32 lanes) does one row, lane = float4 chunk.
__global__ void attr_prep_kernel(const float* __restrict__ ea,
                                 const int* __restrict__ perm,
                                 ushort_t* __restrict__ attr_bf) {
    int t = threadIdx.x;
    int half = t >> 5;
    int ch = t & 31;
    int r = blockIdx.x * 8 + half;
    int pe = perm[r];
    float4 v = make_float4(0.f, 0.f, 0.f, 0.f);
    if (ch < 25) v = *(const float4*)(ea + (size_t)pe * G + ch * 4);
    uint2 p; p.x = pack2(v.x, v.y); p.y = pack2(v.z, v.w);
    *(uint2*)(attr_bf + (size_t)r * 128 + ch * 4) = p;
}

__global__ void cmask_kernel(const float* __restrict__ el, const int* __restrict__ perm,
                             float* __restrict__ c_mask) {
    int e = blockIdx.x * 256 + threadIdx.x;
    c_mask[e] = (el[perm[e]] <= CUTOFF_V) ? 1.0f : 0.0f;
}

// ---------------------------------------------------------------------------
// Edge MLP v2: 64 edges/block, 4 waves, wave-private 16-edge strip, no syncs.
// GEMM1 B-frags stream straight from global attr_bf (coalesced); LDS only for u.
__global__ __launch_bounds__(256, 8) void edge_mlp_kernel(
    const ushort_t* __restrict__ attr_bf, const float* __restrict__ c_mask,
    const ushort_t* __restrict__ w1b, const float* __restrict__ b1,
    const ushort_t* __restrict__ w2b, const float* __restrict__ b2,
    ushort_t* __restrict__ wf) {
    __shared__ __align__(16) ushort_t sU[64][136];

    int t = threadIdx.x, lane = t & 63, wid = t >> 6;
    int c = lane & 15, quad = lane >> 4;
    int e0 = blockIdx.x * 64, rbase = wid * 16;
    int erow = e0 + rbase + c;

    // GEMM1: u_pre = W1 . attr^T
    bf16x8 b[4];
#pragma unroll
    for (int ks = 0; ks < 4; ++ks)
        b[ks] = *(const bf16x8*)(attr_bf + (size_t)erow * 128 + ks * 32 + quad * 8);
    f32x4 acc[8];
#pragma unroll
    for (int i = 0; i < 8; ++i) acc[i] = (f32x4){0.f, 0.f, 0.f, 0.f};
#pragma unroll
    for (int ct = 0; ct < 8; ++ct)
#pragma unroll
        for (int ks = 0; ks < 4; ++ks) {
            bf16x8 a = *(const bf16x8*)(w1b + (size_t)(ct * 16 + c) * 128 + ks * 32 + quad * 8);
            acc[ct] = mfma_bf16(a, b[ks], acc[ct]);
        }
    // epi1: u = ssp(acc + b1) -> sU (lane holds 4 consecutive ucols of edge c)
#pragma unroll
    for (int ct = 0; ct < 8; ++ct) {
        int col = ct * 16 + quad * 4;
        float4 bv = *(const float4*)(b1 + col);
        uint2 p;
        p.x = pack2(sspf(acc[ct][0] + bv.x), sspf(acc[ct][1] + bv.y));
        p.y = pack2(sspf(acc[ct][2] + bv.z), sspf(acc[ct][3] + bv.w));
        *(uint2*)(&sU[rbase + c][col]) = p;
    }

    // GEMM2: Wf_pre = W2 . u^T
#pragma unroll
    for (int ks = 0; ks < 4; ++ks)
        b[ks] = *(const bf16x8*)(&sU[rbase + c][ks * 32 + quad * 8]);
#pragma unroll
    for (int i = 0; i < 8; ++i) acc[i] = (f32x4){0.f, 0.f, 0.f, 0.f};
#pragma unroll
    for (int ct = 0; ct < 8; ++ct)
#pragma unroll
        for (int ks = 0; ks < 4; ++ks) {
            bf16x8 a = *(const bf16x8*)(w2b + (size_t)(ct * 16 + c) * 128 + ks * 32 + quad * 8);
            acc[ct] = mfma_bf16(a, b[ks], acc[ct]);
        }
    // epi2: (acc + b2) * C -> wf, direct 8B stores
    float cv = c_mask[erow];
#pragma unroll
    for (int ct = 0; ct < 8; ++ct) {
        int col = ct * 16 + quad * 4;
        float4 bv = *(const float4*)(b2 + col);
        uint2 p;
        p.x = pack2((acc[ct][0] + bv.x) * cv, (acc[ct][1] + bv.y) * cv);
        p.y = pack2((acc[ct][2] + bv.z) * cv, (acc[ct][3] + bv.w) * cv);
        *(uint2*)(wf + (size_t)erow * 128 + col) = p;
    }
}

// ---------------------------------------------------------------------------
// xf = h @ lin1^T (bf16 out), transposed MFMA; 128 nodes/block (round-3 proven).
template <bool HASB, bool SSP, bool RES, bool BF16OUT, bool TWOK>
__global__ __launch_bounds__(256) void node_mfma_kernel(
    const float* __restrict__ in0, const float* __restrict__ in1,
    const ushort_t* __restrict__ Wb, const float* __restrict__ bias,
    const float* __restrict__ resid, void* __restrict__ outp) {
    __shared__ __align__(16) ushort_t sT[128][136];
    const int WS = TWOK ? 256 : 128;
    int t = threadIdx.x, lane = t & 63, wid = t >> 6;
    int c = lane & 15, quad = lane >> 4;
    int n0 = blockIdx.x * 128, rbase = wid * 32;

    f32x4 acc[2][8];
#pragma unroll
    for (int st = 0; st < 2; ++st)
#pragma unroll
        for (int ct = 0; ct < 8; ++ct) acc[st][ct] = (f32x4){0.f, 0.f, 0.f, 0.f};

    const float* src = in0;
#pragma unroll 1
    for (int ph = 0; ph < (TWOK ? 2 : 1); ++ph) {
#pragma unroll
        for (int i = 0; i < 16; ++i) {
            int idx = i * 64 + lane;
            int r = idx >> 5, ch = idx & 31;
            int gr = n0 + rbase + r;
            float4 v = make_float4(0.f, 0.f, 0.f, 0.f);
            if (gr < N_NODES) v = *(const float4*)(src + (size_t)gr * 128 + ch * 4);
            uint2 p; p.x = pack2(v.x, v.y); p.y = pack2(v.z, v.w);
            *(uint2*)(&sT[rbase + r][ch * 4]) = p;
        }
        int kb = ph * 128;
#pragma unroll
        for (int ks = 0; ks < 4; ++ks) {
            int koff = ks * 32 + quad * 8;
            bf16x8 b0 = *(const bf16x8*)(&sT[rbase + c][koff]);
            bf16x8 b1v = *(const bf16x8*)(&sT[rbase + 16 + c][koff]);
#pragma unroll
            for (int ct = 0; ct < 8; ++ct) {
                bf16x8 a = *(const bf16x8*)(Wb + (size_t)(ct * 16 + c) * WS + kb + koff);
                acc[0][ct] = mfma_bf16(a, b0, acc[0][ct]);
                acc[1][ct] = mfma_bf16(a, b1v, acc[1][ct]);
            }
        }
        src = in1;
    }

#pragma unroll
    for (int st = 0; st < 2; ++st) {
        int node = n0 + rbase + st * 16 + c;
        if (node < N_NODES) {
#pragma unroll
            for (int ct = 0; ct < 8; ++ct) {
                int col = ct * 16 + quad * 4;
                float4 bv = make_float4(0.f, 0.f, 0.f, 0.f);
                if (HASB) bv = *(const float4*)(bias + col);
                float v0 = acc[st][ct][0] + bv.x;
                float v1 = acc[st][ct][1] + bv.y;
                float v2 = acc[st][ct][2] + bv.z;
                float v3 = acc[st][ct][3] + bv.w;
                if (SSP) { v0 = sspf(v0); v1 = sspf(v1); v2 = sspf(v2); v3 = sspf(v3); }
                if (RES) {
                    float4 rv = *(const float4*)(resid + (size_t)node * 128 + col);
                    v0 += rv.x; v1 += rv.y; v2 += rv.z; v3 += rv.w;
                }
                if (BF16OUT) {
                    uint2 p; p.x = pack2(v0, v1); p.y = pack2(v2, v3);
                    *(uint2*)((ushort_t*)outp + (size_t)node * 128 + col) = p;
                } else {
                    *(float4*)((float*)outp + (size_t)node * 128 + col) =
                        make_float4(v0, v1, v2, v3);
                }
            }
        }
    }
}

// ---------------------------------------------------------------------------
// Fused: m = ssp(m_i @ lin2^T + b2l); h += concat(h, m) @ lin_w^T + bl
// 64 nodes/block, wave-private 16-node strips; 3 chained GEMMs.
__global__ __launch_bounds__(256, 8) void update_fused_kernel(
    float* __restrict__ h, const float* __restrict__ m_i,
    const ushort_t* __restrict__ lin2b, const float* __restrict__ lin2_b,
    const ushort_t* __restrict__ linwb, const float* __restrict__ lin_b) {
    __shared__ __align__(16) ushort_t sM[64][136];
    int t = threadIdx.x, lane = t & 63, wid = t >> 6;
    int c = lane & 15, quad = lane >> 4;
    int n0 = blockIdx.x * 64, rbase = wid * 16;

    // stage own 16 rows of m_i (fp32 -> bf16 LDS)
#pragma unroll
    for (int i = 0; i < 8; ++i) {
        int idx = i * 64 + lane;
        int r = idx >> 5, ch = idx & 31;
        int gr = n0 + rbase + r;
        float4 v = make_float4(0.f, 0.f, 0.f, 0.f);
        if (gr < N_NODES) v = *(const float4*)(m_i + (size_t)gr * 128 + ch * 4);
        uint2 p; p.x = pack2(v.x, v.y); p.y = pack2(v.z, v.w);
        *(uint2*)(&sM[rbase + r][ch * 4]) = p;
    }

    // GEMM A: lin2 . m_i^T
    bf16x8 b[4];
#pragma unroll
    for (int ks = 0; ks < 4; ++ks)
        b[ks] = *(const bf16x8*)(&sM[rbase + c][ks * 32 + quad * 8]);
    f32x4 acc[8];
#pragma unroll
    for (int i = 0; i < 8; ++i) acc[i] = (f32x4){0.f, 0.f, 0.f, 0.f};
#pragma unroll
    for (int ct = 0; ct < 8; ++ct)
#pragma unroll
        for (int ks = 0; ks < 4; ++ks) {
            bf16x8 a = *(const bf16x8*)(lin2b + (size_t)(ct * 16 + c) * 128 + ks * 32 + quad * 8);
            acc[ct] = mfma_bf16(a, b[ks], acc[ct]);
        }
    // epi A: m = ssp(acc + lin2_b) -> sM (overwrite own rows; all reads done)
#pragma unroll
    for (int ct = 0; ct < 8; ++ct) {
        int col = ct * 16 + quad * 4;
        float4 bv = *(const float4*)(lin2_b + col);
        uint2 p;
        p.x = pack2(sspf(acc[ct][0] + bv.x), sspf(acc[ct][1] + bv.y));
        p.y = pack2(sspf(acc[ct][2] + bv.z), sspf(acc[ct][3] + bv.w));
        *(uint2*)(&sM[rbase + c][col]) = p;
    }

    // GEMM B: lin_w[:,128:256] . m^T
#pragma unroll
    for (int ks = 0; ks < 4; ++ks)
        b[ks] = *(const bf16x8*)(&sM[rbase + c][ks * 32 + quad * 8]);
#pragma unroll
    for (int i = 0; i < 8; ++i) acc[i] = (f32x4){0.f, 0.f, 0.f, 0.f};
#pragma unroll
    for (int ct = 0; ct < 8; ++ct)
#pragma unroll
        for (int ks = 0; ks < 4; ++ks) {
            bf16x8 a = *(const bf16x8*)(linwb + (size_t)(ct * 16 + c) * 256 + 128 + ks * 32 + quad * 8);
            acc[ct] = mfma_bf16(a, b[ks], acc[ct]);
        }

    // GEMM C: lin_w[:,0:128] . h^T  (B-frags converted from global fp32 h)
    int gr = n0 + rbase + c;
#pragma unroll
    for (int ks = 0; ks < 4; ++ks) {
        float4 v0 = make_float4(0.f, 0.f, 0.f, 0.f), v1 = v0;
        if (gr < N_NODES) {
            const float* hp = h + (size_t)gr * 128 + ks * 32 + quad * 8;
            v0 = *(const float4*)(hp);
            v1 = *(const float4*)(hp + 4);
        }
        union { bf16x8 v; uint4 u; } hb;
        hb.u.x = pack2(v0.x, v0.y); hb.u.y = pack2(v0.z, v0.w);
        hb.u.z = pack2(v1.x, v1.y); hb.u.w = pack2(v1.z, v1.w);
        b[ks] = hb.v;
    }
#pragma unroll
    for (int ct = 0; ct < 8; ++ct)
#pragma unroll
        for (int ks = 0; ks < 4; ++ks) {
            bf16x8 a = *(const bf16x8*)(linwb + (size_t)(ct * 16 + c) * 256 + ks * 32 + quad * 8);
            acc[ct] = mfma_bf16(a, b[ks], acc[ct]);
        }

    // epilogue: h[node] += acc + lin_b (residual in fp32)
    if (gr < N_NODES) {
#pragma unroll
        for (int ct = 0; ct < 8; ++ct) {
            int col = ct * 16 + quad * 4;
            float4 bv = *(const float4*)(lin_b + col);
            float4 hv = *(const float4*)(h + (size_t)gr * 128 + col);
            *(float4*)(h + (size_t)gr * 128 + col) = make_float4(
                hv.x + acc[ct][0] + bv.x, hv.y + acc[ct][1] + bv.y,
                hv.z + acc[ct][2] + bv.z, hv.w + acc[ct][3] + bv.w);
        }
    }
}

// ---------------------------------------------------------------------------
__global__ __launch_bounds__(256) void segsum_kernel(
    const ushort_t* __restrict__ wf, const ushort_t* __restrict__ xf_bf,
    const int* __restrict__ row_start, const int* __restrict__ src_p,
    float* __restrict__ m_i) {
    int t = threadIdx.x, lane = t & 63;
    int n = blockIdx.x * 4 + (t >> 6);
    int beg = row_start[n], end = row_start[n + 1];
    float a0 = 0.f, a1 = 0.f;
    for (int i = beg; i < end; ++i) {
        uint_t w = *(const uint_t*)(wf + (size_t)i * 128 + lane * 2);
        uint_t x = *(const uint_t*)(xf_bf + (size_t)src_p[i] * 128 + lane * 2);
        a0 += __uint_as_float(w << 16) * __uint_as_float(x << 16);
        a1 += __uint_as_float(w & 0xffff0000u) * __uint_as_float(x & 0xffff0000u);
    }
    *(float2*)(m_i + (size_t)n * 128 + lane * 2) = make_float2(a0, a1);
}

// ---------------------------------------------------------------------------
extern "C" void kernel_launch(void* const* d_in, const int* in_sizes, int n_in,
                              void* d_out, int out_size, void* d_ws, size_t ws_size,
                              hipStream_t stream) {
    const float* z        = (const float*)d_in[0];
    const int*   ei       = (const int*)d_in[1];
    const float* el       = (const float*)d_in[2];
    const float* ea       = (const float*)d_in[3];
    const float* emblin_w = (const float*)d_in[4];
    const float* emblin_b = (const float*)d_in[5];
    const float* mlp_w1   = (const float*)d_in[6];
    const float* mlp_b1   = (const float*)d_in[7];
    const float* mlp_w2   = (const float*)d_in[8];
    const float* mlp_b2   = (const float*)d_in[9];
    const float* lin1_w   = (const float*)d_in[10];
    const float* lin2_w   = (const float*)d_in[11];
    const float* lin2_b   = (const float*)d_in[12];
    const float* lin_w    = (const float*)d_in[13];
    const float* lin_b    = (const float*)d_in[14];
    (void)in_sizes; (void)n_in; (void)out_size; (void)ws_size;

    const size_t ND = (size_t)N_NODES * D;
    float* ws   = (float*)d_ws;
    float* h    = ws;                // N*D fp32
    float* m_i  = h + ND;            // N*D fp32
    float* c_mask = m_i + ND;        // E fp32
    float* fend = c_mask + E_EDGES;

    ushort_t* w1b     = (ushort_t*)fend;                     // L*D*128
    ushort_t* w2b     = w1b   + (size_t)L_LAYERS * D * 128;  // L*D*D
    ushort_t* lin1b   = w2b   + (size_t)L_LAYERS * D * D;    // L*D*D
    ushort_t* lin2b   = lin1b + (size_t)L_LAYERS * D * D;    // L*D*D
    ushort_t* linwb   = lin2b + (size_t)L_LAYERS * D * D;    // L*D*256
    ushort_t* wf      = linwb + (size_t)L_LAYERS * D * 256;  // E*128
    ushort_t* xf_bf   = wf    + (size_t)E_EDGES * 128;       // N*128
    ushort_t* attr_bf = xf_bf + ND;                          // E*128
    int* ibase      = (int*)(attr_bf + (size_t)E_EDGES * 128);
    int* deg        = ibase;                 // N
    int* row_start  = deg + N_NODES;         // N+1
    int* cursor     = row_start + N_NODES + 1;
    int* perm       = cursor + N_NODES;      // E
    int* src_p      = perm + E_EDGES;        // E

    // one-time weight prep
    convw1_kernel<<<(L_LAYERS * D * 128) / 256, 256, 0, stream>>>(mlp_w1, w1b);
    castbf_kernel<<<(L_LAYERS * D * D) / 256, 256, 0, stream>>>(mlp_w2, w2b);
    castbf_kernel<<<(L_LAYERS * D * D) / 256, 256, 0, stream>>>(lin1_w, lin1b);
    castbf_kernel<<<(L_LAYERS * D * D) / 256, 256, 0, stream>>>(lin2_w, lin2b);
    castbf_kernel<<<(L_LAYERS * D * 256) / 256, 256, 0, stream>>>(lin_w, linwb);

    // CSR build, then edge-side one-time prep
    hipMemsetAsync(deg, 0, (size_t)N_NODES * sizeof(int), stream);
    hist_kernel<<<E_EDGES / 256, 256, 0, stream>>>(ei, deg);
    scan_kernel<<<1, 1024, 0, stream>>>(deg, row_start, cursor);
    scatter_perm_kernel<<<E_EDGES / 256, 256, 0, stream>>>(ei, cursor, perm, src_p);
    attr_prep_kernel<<<E_EDGES / 8, 256, 0, stream>>>(ea, perm, attr_bf);
    cmask_kernel<<<E_EDGES / 256, 256, 0, stream>>>(el, perm, c_mask);

    embed_kernel<<<N_NODES, D, 0, stream>>>(z, emblin_w, emblin_b, h);

    const int NBLK = (N_NODES + 127) / 128;   // 157
    const int UBLK = (N_NODES + 63) / 64;     // 313
    for (int l = 0; l < L_LAYERS; ++l) {
        node_mfma_kernel<false, false, false, true, false><<<NBLK, 256, 0, stream>>>(
            h, nullptr, lin1b + (size_t)l * D * D, nullptr, nullptr, xf_bf);
        edge_mlp_kernel<<<E_EDGES / 64, 256, 0, stream>>>(
            attr_bf, c_mask, w1b + (size_t)l * D * 128, mlp_b1 + (size_t)l * D,
            w2b + (size_t)l * D * D, mlp_b2 + (size_t)l * D, wf);
        segsum_kernel<<<N_NODES / 4, 256, 0, stream>>>(wf, xf_bf, row_start, src_p, m_i);
        update_fused_kernel<<<UBLK, 256, 0, stream>>>(
            h, m_i, lin2b + (size_t)l * D * D, lin2_b + (size_t)l * D,
            linwb + (size_t)l * D * 256, lin_b + (size_t)l * D);
    }

    hipMemcpyAsync(d_out, h, ND * sizeof(float), hipMemcpyDeviceToDevice, stream);
}

// Round 5
// 1969.022 us; speedup vs baseline: 1.0307x; 1.0307x over previous
//
#include <hip/hip_runtime.h>

#define N_NODES 20000
#define D 128
#define E_EDGES 320000
#define G 100
#define L_LAYERS 6
#define IN_DIM 5
#define ZROW (IN_DIM + D)
#define CUTOFF_V 10.0f
#define LOG2F_ 0.69314718055994530942f

typedef __attribute__((ext_vector_type(8))) short bf16x8;
typedef __attribute__((ext_vector_type(4))) float f32x4;
typedef unsigned short ushort_t;
typedef unsigned int uint_t;

__device__ __forceinline__ float sspf(float x) {
    return fmaxf(x, 0.0f) + __logf(1.0f + __expf(-fabsf(x))) - LOG2F_;
}

__device__ __forceinline__ ushort_t f2bf(float f) {
    union { float f; uint_t u; } x; x.f = f;
    uint_t r = ((x.u >> 16) & 1u) + 0x7fffu;
    return (ushort_t)((x.u + r) >> 16);
}

__device__ __forceinline__ uint_t pack2(float a, float b) {
    return (uint_t)f2bf(a) | ((uint_t)f2bf(b) << 16);
}

__device__ __forceinline__ float bflo(uint_t u) { return __uint_as_float(u << 16); }
__device__ __forceinline__ float bfhi(uint_t u) { return __uint_as_float(u & 0xffff0000u); }

__device__ __forceinline__ f32x4 mfma_bf16(bf16x8 a, bf16x8 b, f32x4 c) {
    return __builtin_amdgcn_mfma_f32_16x16x32_bf16(a, b, c, 0, 0, 0);
}

// ---------------------------------------------------------------------------
__global__ void embed_kernel(const float* __restrict__ z,
                             const float* __restrict__ ew,
                             const float* __restrict__ eb,
                             float* __restrict__ h) {
    int n = blockIdx.x;
    int d = threadIdx.x;
    const float* zr = z + (size_t)n * ZROW;
    float acc = eb[d] + zr[IN_DIM + d];
#pragma unroll
    for (int k = 0; k < IN_DIM; ++k) acc += zr[k] * ew[d * IN_DIM + k];
    h[(size_t)n * D + d] = acc;
}

// ---------------------------------------------------------------------------
__global__ void convw1_kernel(const float* __restrict__ w1, ushort_t* __restrict__ out) {
    int idx = blockIdx.x * 256 + threadIdx.x;
    int k = idx & 127;
    int nl = idx >> 7;
    out[idx] = (k < G) ? f2bf(w1[(size_t)nl * G + k]) : (ushort_t)0;
}

__global__ void castbf_kernel(const float* __restrict__ src, ushort_t* __restrict__ dst) {
    int i = blockIdx.x * 256 + threadIdx.x;
    dst[i] = f2bf(src[i]);
}

// ---------------------------------------------------------------------------
// CSR build (edge graph constant across layers)
__global__ void hist_kernel(const int* __restrict__ ei, int* __restrict__ deg) {
    int e = blockIdx.x * 256 + threadIdx.x;
    atomicAdd(&deg[ei[E_EDGES + e]], 1);
}

__global__ __launch_bounds__(1024) void scan_kernel(const int* __restrict__ deg,
                                                    int* __restrict__ row_start,
                                                    int* __restrict__ cursor) {
    __shared__ int wsum[16];
    int t = threadIdx.x;
    const int CH = (N_NODES + 1023) / 1024;
    int base = t * CH;
    int s = 0;
    for (int i = 0; i < CH; ++i) {
        int idx = base + i;
        if (idx < N_NODES) s += deg[idx];
    }
    int lane = t & 63, wid = t >> 6;
    int v = s;
    for (int o = 1; o < 64; o <<= 1) {
        int u = __shfl_up(v, o, 64);
        if (lane >= o) v += u;
    }
    if (lane == 63) wsum[wid] = v;
    __syncthreads();
    if (t == 0) {
        int acc = 0;
        for (int i = 0; i < 16; ++i) { int tmp = wsum[i]; wsum[i] = acc; acc += tmp; }
    }
    __syncthreads();
    int run = v - s + wsum[wid];
    for (int i = 0; i < CH; ++i) {
        int idx = base + i;
        if (idx < N_NODES) {
            row_start[idx] = run;
            cursor[idx] = run;
            run += deg[idx];
        }
    }
    if (t == 0) row_start[N_NODES] = E_EDGES;
}

__global__ void scatter_perm_kernel(const int* __restrict__ ei, int* __restrict__ cursor,
                                    int* __restrict__ perm, int* __restrict__ src_p,
                                    int* __restrict__ dst_p) {
    int e = blockIdx.x * 256 + threadIdx.x;
    int d = ei[E_EDGES + e];
    int p = atomicAdd(&cursor[d], 1);
    perm[p] = e;
    src_p[p] = ei[e];
    dst_p[p] = d;
}

// ---------------------------------------------------------------------------
// One-time: attr_bf[i] = bf16(edge_attr[perm[i]]) zero-padded to 128.
__global__ void attr_prep_kernel(const float* __restrict__ ea,
                                 const int* __restrict__ perm,
                                 ushort_t* __restrict__ attr_bf) {
    int t = threadIdx.x;
    int half = t >> 5;
    int ch = t & 31;
    int r = blockIdx.x * 8 + half;
    int pe = perm[r];
    float4 v = make_float4(0.f, 0.f, 0.f, 0.f);
    if (ch < 25) v = *(const float4*)(ea + (size_t)pe * G + ch * 4);
    uint2 p; p.x = pack2(v.x, v.y); p.y = pack2(v.z, v.w);
    *(uint2*)(attr_bf + (size_t)r * 128 + ch * 4) = p;
}

__global__ void cmask_kernel(const float* __restrict__ el, const int* __restrict__ perm,
                             float* __restrict__ c_mask) {
    int e = blockIdx.x * 256 + threadIdx.x;
    c_mask[e] = (el[perm[e]] <= CUTOFF_V) ? 1.0f : 0.0f;
}

// ---------------------------------------------------------------------------
// Fused edge MLP + segment sum. 64 edges/block, 4 waves, wave-private
// 16-edge strips (edges sorted by dst). Per strip:
//   Wf = (W2.ssp(W1.attr^T + b1) + b2)*C          (2 MFMA GEMMs)
//   prod = Wf * xf[src]  -> fp32 LDS (reuses the dead u-strip: both 4352 B)
//   each lane reduces one column over the 16 edges; interior dst segments
//   plain-store to m_i, strip-boundary segments fp32 atomicAdd (m_i memset 0).
// Branches in the reduction are wave-uniform (dst is lane-invariant).
__global__ __launch_bounds__(256, 8) void edge_fused_kernel(
    const ushort_t* __restrict__ attr_bf, const float* __restrict__ c_mask,
    const int* __restrict__ src_p, const int* __restrict__ dst_p,
    const ushort_t* __restrict__ xf_bf,
    const ushort_t* __restrict__ w1b, const float* __restrict__ b1,
    const ushort_t* __restrict__ w2b, const float* __restrict__ b2,
    float* __restrict__ m_i) {
    __shared__ __align__(16) ushort_t sU[4][16 * 136];   // per-wave 4352 B
    __shared__ int s_dst[64];
    __shared__ int s_src[64];

    int t = threadIdx.x, lane = t & 63, wid = t >> 6;
    int c = lane & 15, quad = lane >> 4;
    int e0 = blockIdx.x * 64, rbase = wid * 16;
    int erow = e0 + rbase + c;

    if (t < 64) {
        s_dst[t] = dst_p[e0 + t];
        s_src[t] = src_p[e0 + t];
    }
    __syncthreads();

    // GEMM1: u_pre = W1 . attr^T  (B-frags coalesced from global)
    bf16x8 b[4];
#pragma unroll
    for (int ks = 0; ks < 4; ++ks)
        b[ks] = *(const bf16x8*)(attr_bf + (size_t)erow * 128 + ks * 32 + quad * 8);
    f32x4 acc[8];
#pragma unroll
    for (int i = 0; i < 8; ++i) acc[i] = (f32x4){0.f, 0.f, 0.f, 0.f};
#pragma unroll
    for (int ct = 0; ct < 8; ++ct)
#pragma unroll
        for (int ks = 0; ks < 4; ++ks) {
            bf16x8 a = *(const bf16x8*)(w1b + (size_t)(ct * 16 + c) * 128 + ks * 32 + quad * 8);
            acc[ct] = mfma_bf16(a, b[ks], acc[ct]);
        }
    // epi1: u = ssp(acc + b1) -> own sU strip
#pragma unroll
    for (int ct = 0; ct < 8; ++ct) {
        int col = ct * 16 + quad * 4;
        float4 bv = *(const float4*)(b1 + col);
        uint2 p;
        p.x = pack2(sspf(acc[ct][0] + bv.x), sspf(acc[ct][1] + bv.y));
        p.y = pack2(sspf(acc[ct][2] + bv.z), sspf(acc[ct][3] + bv.w));
        *(uint2*)(&sU[wid][c * 136 + col]) = p;
    }

    // GEMM2: Wf_pre = W2 . u^T
#pragma unroll
    for (int ks = 0; ks < 4; ++ks)
        b[ks] = *(const bf16x8*)(&sU[wid][c * 136 + ks * 32 + quad * 8]);
#pragma unroll
    for (int i = 0; i < 8; ++i) acc[i] = (f32x4){0.f, 0.f, 0.f, 0.f};
#pragma unroll
    for (int ct = 0; ct < 8; ++ct)
#pragma unroll
        for (int ks = 0; ks < 4; ++ks) {
            bf16x8 a = *(const bf16x8*)(w2b + (size_t)(ct * 16 + c) * 128 + ks * 32 + quad * 8);
            acc[ct] = mfma_bf16(a, b[ks], acc[ct]);
        }

    // fused xf-multiply + segmented reduction, two 64-col passes
    float cv = c_mask[erow];
    int srcn = s_src[rbase + c];
    float* sP = (float*)&sU[wid][0];   // [16 edges][68] fp32, exactly 4352 B
#pragma unroll 1
    for (int p = 0; p < 2; ++p) {
        // products -> LDS (b128 writes; 68-stride keeps banks at free 2-way)
#pragma unroll
        for (int ctl = 0; ctl < 4; ++ctl) {
            int ct = p * 4 + ctl;
            int col = ct * 16 + quad * 4;
            float4 bv = *(const float4*)(b2 + col);
            uint2 xr = *(const uint2*)(xf_bf + (size_t)srcn * 128 + col);
            float4 pr;
            pr.x = (acc[ct][0] + bv.x) * cv * bflo(xr.x);
            pr.y = (acc[ct][1] + bv.y) * cv * bfhi(xr.x);
            pr.z = (acc[ct][2] + bv.z) * cv * bflo(xr.y);
            pr.w = (acc[ct][3] + bv.w) * cv * bfhi(xr.y);
            *(float4*)(sP + c * 68 + ctl * 16 + quad * 4) = pr;
        }
        // lane j reduces column p*64+j over the strip's 16 edges
        int j = lane;
        float s = 0.f;
        int a0 = 0;
        int dprev = s_dst[rbase];
#pragma unroll 1
        for (int e = 0; e < 16; ++e) {
            int d = s_dst[rbase + e];
            if (d != dprev) {
                float* dp = m_i + (size_t)dprev * 128 + p * 64 + j;
                if (a0 > 0) *dp = s;          // interior segment: exclusive owner
                else atomicAdd(dp, s);        // may extend into previous strip
                s = 0.f; a0 = e; dprev = d;
            }
            s += sP[e * 68 + j];
        }
        atomicAdd(m_i + (size_t)dprev * 128 + p * 64 + j, s);  // may extend right
    }
}

// ---------------------------------------------------------------------------
// Node GEMM on MFMA (round-3 proven): 128 nodes/block.
template <bool HASB, bool SSP, bool RES, bool BF16OUT, bool TWOK>
__global__ __launch_bounds__(256) void node_mfma_kernel(
    const float* __restrict__ in0, const float* __restrict__ in1,
    const ushort_t* __restrict__ Wb, const float* __restrict__ bias,
    const float* __restrict__ resid, void* __restrict__ outp) {
    __shared__ __align__(16) ushort_t sT[128][136];
    const int WS = TWOK ? 256 : 128;
    int t = threadIdx.x, lane = t & 63, wid = t >> 6;
    int c = lane & 15, quad = lane >> 4;
    int n0 = blockIdx.x * 128, rbase = wid * 32;

    f32x4 acc[2][8];
#pragma unroll
    for (int st = 0; st < 2; ++st)
#pragma unroll
        for (int ct = 0; ct < 8; ++ct) acc[st][ct] = (f32x4){0.f, 0.f, 0.f, 0.f};

    const float* src = in0;
#pragma unroll 1
    for (int ph = 0; ph < (TWOK ? 2 : 1); ++ph) {
#pragma unroll
        for (int i = 0; i < 16; ++i) {
            int idx = i * 64 + lane;
            int r = idx >> 5, ch = idx & 31;
            int gr = n0 + rbase + r;
            float4 v = make_float4(0.f, 0.f, 0.f, 0.f);
            if (gr < N_NODES) v = *(const float4*)(src + (size_t)gr * 128 + ch * 4);
            uint2 p; p.x = pack2(v.x, v.y); p.y = pack2(v.z, v.w);
            *(uint2*)(&sT[rbase + r][ch * 4]) = p;
        }
        int kb = ph * 128;
#pragma unroll
        for (int ks = 0; ks < 4; ++ks) {
            int koff = ks * 32 + quad * 8;
            bf16x8 b0 = *(const bf16x8*)(&sT[rbase + c][koff]);
            bf16x8 b1v = *(const bf16x8*)(&sT[rbase + 16 + c][koff]);
#pragma unroll
            for (int ct = 0; ct < 8; ++ct) {
                bf16x8 a = *(const bf16x8*)(Wb + (size_t)(ct * 16 + c) * WS + kb + koff);
                acc[0][ct] = mfma_bf16(a, b0, acc[0][ct]);
                acc[1][ct] = mfma_bf16(a, b1v, acc[1][ct]);
            }
        }
        src = in1;
    }

#pragma unroll
    for (int st = 0; st < 2; ++st) {
        int node = n0 + rbase + st * 16 + c;
        if (node < N_NODES) {
#pragma unroll
            for (int ct = 0; ct < 8; ++ct) {
                int col = ct * 16 + quad * 4;
                float4 bv = make_float4(0.f, 0.f, 0.f, 0.f);
                if (HASB) bv = *(const float4*)(bias + col);
                float v0 = acc[st][ct][0] + bv.x;
                float v1 = acc[st][ct][1] + bv.y;
                float v2 = acc[st][ct][2] + bv.z;
                float v3 = acc[st][ct][3] + bv.w;
                if (SSP) { v0 = sspf(v0); v1 = sspf(v1); v2 = sspf(v2); v3 = sspf(v3); }
                if (RES) {
                    float4 rv = *(const float4*)(resid + (size_t)node * 128 + col);
                    v0 += rv.x; v1 += rv.y; v2 += rv.z; v3 += rv.w;
                }
                if (BF16OUT) {
                    uint2 p; p.x = pack2(v0, v1); p.y = pack2(v2, v3);
                    *(uint2*)((ushort_t*)outp + (size_t)node * 128 + col) = p;
                } else {
                    *(float4*)((float*)outp + (size_t)node * 128 + col) =
                        make_float4(v0, v1, v2, v3);
                }
            }
        }
    }
}

// ---------------------------------------------------------------------------
extern "C" void kernel_launch(void* const* d_in, const int* in_sizes, int n_in,
                              void* d_out, int out_size, void* d_ws, size_t ws_size,
                              hipStream_t stream) {
    const float* z        = (const float*)d_in[0];
    const int*   ei       = (const int*)d_in[1];
    const float* el       = (const float*)d_in[2];
    const float* ea       = (const float*)d_in[3];
    const float* emblin_w = (const float*)d_in[4];
    const float* emblin_b = (const float*)d_in[5];
    const float* mlp_w1   = (const float*)d_in[6];
    const float* mlp_b1   = (const float*)d_in[7];
    const float* mlp_w2   = (const float*)d_in[8];
    const float* mlp_b2   = (const float*)d_in[9];
    const float* lin1_w   = (const float*)d_in[10];
    const float* lin2_w   = (const float*)d_in[11];
    const float* lin2_b   = (const float*)d_in[12];
    const float* lin_w    = (const float*)d_in[13];
    const float* lin_b    = (const float*)d_in[14];
    (void)in_sizes; (void)n_in; (void)out_size; (void)ws_size;

    const size_t ND = (size_t)N_NODES * D;
    float* ws   = (float*)d_ws;
    float* h    = ws;                // N*D fp32
    float* m_i  = h + ND;            // N*D fp32
    float* c_mask = m_i + ND;        // E fp32
    float* fend = c_mask + E_EDGES;

    ushort_t* w1b     = (ushort_t*)fend;                     // L*D*128
    ushort_t* w2b     = w1b   + (size_t)L_LAYERS * D * 128;  // L*D*D
    ushort_t* lin1b   = w2b   + (size_t)L_LAYERS * D * D;    // L*D*D
    ushort_t* lin2b   = lin1b + (size_t)L_LAYERS * D * D;    // L*D*D
    ushort_t* linwb   = lin2b + (size_t)L_LAYERS * D * D;    // L*D*256
    ushort_t* xf_bf   = linwb + (size_t)L_LAYERS * D * 256;  // N*128
    ushort_t* attr_bf = xf_bf + ND;                          // E*128
    int* ibase      = (int*)(attr_bf + (size_t)E_EDGES * 128);
    int* deg        = ibase;                 // N
    int* row_start  = deg + N_NODES;         // N+1
    int* cursor     = row_start + N_NODES + 1;
    int* perm       = cursor + N_NODES;      // E
    int* src_p      = perm + E_EDGES;        // E
    int* dst_p      = src_p + E_EDGES;       // E

    // one-time weight prep
    convw1_kernel<<<(L_LAYERS * D * 128) / 256, 256, 0, stream>>>(mlp_w1, w1b);
    castbf_kernel<<<(L_LAYERS * D * D) / 256, 256, 0, stream>>>(mlp_w2, w2b);
    castbf_kernel<<<(L_LAYERS * D * D) / 256, 256, 0, stream>>>(lin1_w, lin1b);
    castbf_kernel<<<(L_LAYERS * D * D) / 256, 256, 0, stream>>>(lin2_w, lin2b);
    castbf_kernel<<<(L_LAYERS * D * 256) / 256, 256, 0, stream>>>(lin_w, linwb);

    // CSR build + edge-side one-time prep
    hipMemsetAsync(deg, 0, (size_t)N_NODES * sizeof(int), stream);
    hist_kernel<<<E_EDGES / 256, 256, 0, stream>>>(ei, deg);
    scan_kernel<<<1, 1024, 0, stream>>>(deg, row_start, cursor);
    scatter_perm_kernel<<<E_EDGES / 256, 256, 0, stream>>>(ei, cursor, perm, src_p, dst_p);
    attr_prep_kernel<<<E_EDGES / 8, 256, 0, stream>>>(ea, perm, attr_bf);
    cmask_kernel<<<E_EDGES / 256, 256, 0, stream>>>(el, perm, c_mask);

    embed_kernel<<<N_NODES, D, 0, stream>>>(z, emblin_w, emblin_b, h);

    const int NBLK = (N_NODES + 127) / 128;   // 157
    for (int l = 0; l < L_LAYERS; ++l) {
        hipMemsetAsync(m_i, 0, ND * sizeof(float), stream);
        // xf_bf = h @ lin1^T (bf16 out)
        node_mfma_kernel<false, false, false, true, false><<<NBLK, 256, 0, stream>>>(
            h, nullptr, lin1b + (size_t)l * D * D, nullptr, nullptr, xf_bf);
        // fused edge MLP + segment sum -> m_i
        edge_fused_kernel<<<E_EDGES / 64, 256, 0, stream>>>(
            attr_bf, c_mask, src_p, dst_p, xf_bf,
            w1b + (size_t)l * D * 128, mlp_b1 + (size_t)l * D,
            w2b + (size_t)l * D * D, mlp_b2 + (size_t)l * D, m_i);
        // m_i = ssp(m_i @ lin2^T + b) in place
        node_mfma_kernel<true, true, false, false, false><<<NBLK, 256, 0, stream>>>(
            m_i, nullptr, lin2b + (size_t)l * D * D, lin2_b + (size_t)l * D,
            nullptr, m_i);
        // h = h + concat(h, m_i) @ lin_w^T + b in place
        node_mfma_kernel<true, false, true, false, true><<<NBLK, 256, 0, stream>>>(
            h, m_i, linwb + (size_t)l * D * 256, lin_b + (size_t)l * D, h, h);
    }

    hipMemcpyAsync(d_out, h, ND * sizeof(float), hipMemcpyDeviceToDevice, stream);
}